// Round 14
// baseline (162.148 us; speedup 1.0000x reference)
//
#include <hip/hip_runtime.h>
#include <hip/hip_bf16.h>

typedef __attribute__((ext_vector_type(8))) short short8;     // 8 bf16 MFMA operand
typedef __attribute__((ext_vector_type(4))) float f32x4;
typedef __attribute__((ext_vector_type(8))) unsigned short ushort8v;

// B=2, T=2048, D_IN=1024, H=16, D_HEAD=64, D_INNER=1024, M=B*T=4096

__device__ __forceinline__ unsigned short f2bf(float f) {
  union { float f; unsigned int u; } x; x.f = f;
  unsigned int r = x.u + 0x7FFFu + ((x.u >> 16) & 1u);   // RNE
  return (unsigned short)(r >> 16);
}

// packed f32x2 -> bf16x2 (v_cvt_pk_bf16_f32 on gfx950): 1 instr vs ~8 manual
__device__ __forceinline__ unsigned int pk_bf16(float a, float b) {
  __hip_bfloat162 h = __float22bfloat162_rn(float2{a, b});
  union { __hip_bfloat162 h; unsigned int u; } c; c.h = h;
  return c.u;
}

__device__ __forceinline__ void gload_lds16(const void* g, void* l) {
  __builtin_amdgcn_global_load_lds(
      (const __attribute__((address_space(1))) void*)g,
      (__attribute__((address_space(3))) void*)l, 16, 0, 0);
}

// ---------------- fused prep: bias_init + x->bf16 + 4 weight transposes ----------------
// grid: [0,4096) cvt x | [4096,7168) Wq/Wk/Wv transpose | [7168,7232) Wo | [7232,7488) bias

__global__ __launch_bounds__(256) void prep(
    const float* __restrict__ x,
    const float* __restrict__ Wq, const float* __restrict__ Wk, const float* __restrict__ Wv,
    const float* __restrict__ Wo, const float* __restrict__ bo,
    unsigned short* __restrict__ xb,
    unsigned short* __restrict__ wqt, unsigned short* __restrict__ wkt,
    unsigned short* __restrict__ wvt, unsigned short* __restrict__ wot,
    float* __restrict__ out) {
  __shared__ float tile[32][33];
  int b = blockIdx.x;
  if (b < 4096) {                     // x -> bf16, 4 elems/thread (packed cvt)
    int i = (b * 256 + threadIdx.x) * 4;
    float4 f = *(const float4*)(x + i);
    uint2 o; o.x = pk_bf16(f.x, f.y); o.y = pk_bf16(f.z, f.w);
    *(uint2*)(xb + i) = o;
  } else if (b < 7168) {              // W^T for Wq/Wk/Wv (1024x1024)
    int idx = b - 4096;
    int z = idx >> 10, rem = idx & 1023;
    const float* src = (z == 0) ? Wq : (z == 1) ? Wk : Wv;
    unsigned short* dst = (z == 0) ? wqt : (z == 1) ? wkt : wvt;
    int kx = (rem & 31) * 32, ny = (rem >> 5) * 32;
    int tx = threadIdx.x & 31, ty = threadIdx.x >> 5;
    #pragma unroll
    for (int r = 0; r < 32; r += 8)
      tile[ty + r][tx] = src[(size_t)(kx + ty + r) * 1024 + ny + tx];
    __syncthreads();
    #pragma unroll
    for (int r = 0; r < 32; r += 8)
      dst[(size_t)(ny + ty + r) * 1024 + kx + tx] = f2bf(tile[tx][ty + r]);
  } else if (b < 7232) {              // Wo^T (1024x64 -> 64x1024)
    int idx = b - 7168;
    int kx = (idx & 31) * 32, ny = (idx >> 5) * 32;
    int tx = threadIdx.x & 31, ty = threadIdx.x >> 5;
    #pragma unroll
    for (int r = 0; r < 32; r += 8)
      tile[ty + r][tx] = Wo[(size_t)(kx + ty + r) * 64 + ny + tx];
    __syncthreads();
    #pragma unroll
    for (int r = 0; r < 32; r += 8)
      wot[(size_t)(ny + ty + r) * 1024 + kx + tx] = f2bf(tile[tx][ty + r]);
  } else {                            // seed out with bias (out is re-poisoned each call)
    int t = (b - 7232) * 256 + threadIdx.x;  // 65536 float4s
    float4 bi = *(const float4*)(bo + (t & 15) * 4);
    *(float4*)(out + (size_t)t * 4) = bi;
  }
}

// ---------------- QKV projection GEMM, BK=64, XOR-swizzled staging ----------------
// Operand roles chosen so the 4 in-lane C regs are consecutive in the OUTPUT's
// fastest dim -> epilogue packs bf16 pairs (v_cvt_pk) and stores b64.
// z=0/1: A=W^T (m over d_inner), B=x (n over tokens) -> D[d][t].
// z=2:   A=x (m over tokens), B=Wv^T (n over d_inner) -> D[t][d].

__global__ __launch_bounds__(256) void qkv_gemm(
    const unsigned short* __restrict__ Xb,
    const unsigned short* __restrict__ Wqt, const unsigned short* __restrict__ Wkt,
    const unsigned short* __restrict__ Wvt,
    unsigned short* __restrict__ Oq, unsigned short* __restrict__ Ok,
    unsigned short* __restrict__ Ovt) {
  constexpr int Kd = 1024;
  __shared__ __align__(16) unsigned short As[128 * 64];
  __shared__ __align__(16) unsigned short Bs[128 * 64];
  int z = blockIdx.z;
  int m0, n0;
  const unsigned short *Arow, *Brow;
  if (z == 2) {          // m tokens (32 tiles), n d_inner (8 tiles)
    m0 = blockIdx.x * 128; n0 = blockIdx.y * 128;
    Arow = Xb; Brow = Wvt;
  } else {               // m d_inner (8 tiles), n tokens (32 tiles)
    m0 = blockIdx.y * 128; n0 = blockIdx.x * 128;
    Arow = (z == 0) ? Wqt : Wkt; Brow = Xb;
  }
  int tid = threadIdx.x, lane = tid & 63, wave = tid >> 6;
  int wm = wave >> 1, wn = wave & 1;
  int l15 = lane & 15, quad = lane >> 4;
  int swz = l15 & 7;

  f32x4 acc[4][4] = {};

  for (int k0 = 0; k0 < Kd; k0 += 64) {
    __syncthreads();
    #pragma unroll
    for (int r = 0; r < 4; ++r) {
      int i = tid + 256 * r;
      int row = i >> 3, c8 = i & 7;
      int gc8 = c8 ^ (row & 7);
      gload_lds16(Arow + (size_t)(m0 + row) * Kd + k0 + gc8 * 8, &As[i * 8]);
    }
    #pragma unroll
    for (int r = 0; r < 4; ++r) {
      int i = tid + 256 * r;
      int row = i >> 3, c8 = i & 7;
      int gc8 = c8 ^ (row & 7);
      gload_lds16(Brow + (size_t)(n0 + row) * Kd + k0 + gc8 * 8, &Bs[i * 8]);
    }
    __syncthreads();
    short8 af[4][2], bf[4][2];
    #pragma unroll
    for (int s = 0; s < 2; ++s) {
      #pragma unroll
      for (int i = 0; i < 4; ++i)
        af[i][s] = *(const short8*)&As[(wm * 64 + i * 16 + l15) * 64 + (((s << 2) + quad) ^ swz) * 8];
      #pragma unroll
      for (int j = 0; j < 4; ++j)
        bf[j][s] = *(const short8*)&Bs[(wn * 64 + j * 16 + l15) * 64 + (((s << 2) + quad) ^ swz) * 8];
    }
    #pragma unroll
    for (int s = 0; s < 2; ++s)
      #pragma unroll
      for (int i = 0; i < 4; ++i)
        #pragma unroll
        for (int j = 0; j < 4; ++j)
          acc[i][j] = __builtin_amdgcn_mfma_f32_16x16x32_bf16(af[i][s], bf[j][s], acc[i][j], 0, 0, 0);
  }

  if (z == 2) {
    // D[t][d] -> Vt[(b*16+h)*64+d][t], pack 4 consecutive t per lane -> b64
    #pragma unroll
    for (int i = 0; i < 4; ++i) {
      int tbase = m0 + wm * 64 + i * 16 + quad * 4;
      int b = tbase >> 11, tt = tbase & 2047;
      #pragma unroll
      for (int j = 0; j < 4; ++j) {
        int dm = n0 + wn * 64 + j * 16 + l15;
        int h = dm >> 6, d = dm & 63;
        uint2 pk;
        pk.x = pk_bf16(acc[i][j][0], acc[i][j][1]);
        pk.y = pk_bf16(acc[i][j][2], acc[i][j][3]);
        *(uint2*)(Ovt + (((size_t)(b * 16 + h) * 64 + d) << 11) + tt) = pk;
      }
    }
  } else {
    // D[d][t] -> O[(b*16+h)*2048+t][d], pack 4 consecutive d per lane -> b64
    unsigned short* O = (z == 0) ? Oq : Ok;
    float scale = (z == 0) ? 0.03125f : 1.0f;  // 1/sqrt(1024) folded into Q
    #pragma unroll
    for (int i = 0; i < 4; ++i) {
      int dmbase = m0 + wm * 64 + i * 16 + quad * 4;
      int h = dmbase >> 6, d0 = dmbase & 63;
      #pragma unroll
      for (int j = 0; j < 4; ++j) {
        int t = n0 + wn * 64 + j * 16 + l15;
        int b = t >> 11, tt = t & 2047;
        uint2 pk;
        pk.x = pk_bf16(acc[i][j][0] * scale, acc[i][j][1] * scale);
        pk.y = pk_bf16(acc[i][j][2] * scale, acc[i][j][3] * scale);
        *(uint2*)(O + (((size_t)(b * 16 + h) * 2048 + tt) << 6) + d0) = pk;
      }
    }
  }
}

// ---------------- fused causal flash attention v10: merged dual-tile + packed cvt ----------------
// attn9 structure (merged dual-tile waves: light qtA=pp + heavy qtB=31-pp,
// shared staged k-tiles in loop1, per-CU work constant across complement
// pairs co-resident via pp = by<8 ? by : 23-by) with ONE change: all bf16
// packing uses v_cvt_pk_bf16_f32 (1 instr/pair vs ~8 manual) — the pack sat
// serially between S-MFMA and PV-MFMA on every wave's critical path.

__global__ __launch_bounds__(256, 2) void attn10(
    const unsigned short* __restrict__ Qg, const unsigned short* __restrict__ Kg,
    const unsigned short* __restrict__ Vtg, unsigned short* __restrict__ Yg) {
  constexpr int T = 2048;
  __shared__ __align__(16) unsigned short Ks[64 * 72];   // [tok][d]
  __shared__ __align__(16) unsigned short Vs[64 * 72];   // [d][tok]
  __shared__ __align__(16) unsigned short Ps[4][32 * 72];
  int bh = blockIdx.x;
  int by = blockIdx.y;
  int pp = (by < 8) ? by : 23 - by;        // blocks (bx,by),(bx,by+8): same bh, complement pp
  int qtA = pp, qtB = 31 - pp;             // light, heavy 64-row q-tiles
  int tid = threadIdx.x, lane = tid & 63, wave = tid >> 6;
  int l15 = lane & 15, quad = lane >> 4;
  const unsigned short* Qb = Qg + (size_t)bh * T * 64;
  const unsigned short* Kb = Kg + (size_t)bh * T * 64;
  const unsigned short* Vb = Vtg + (size_t)bh * 64 * T;
  int h = bh & 15, b = bh >> 4;
  int qw[2] = {qtA * 64 + wave * 16, qtB * 64 + wave * 16};

  // Q as B-operand frags (regs): lane n=q(l15), k=d(quad*8+32s)
  short8 qf[2][2];
  #pragma unroll
  for (int jq = 0; jq < 2; ++jq)
    #pragma unroll
    for (int s = 0; s < 2; ++s)
      qf[jq][s] = *(const short8*)(Qb + (size_t)(qw[jq] + l15) * 64 + quad * 8 + 32 * s);

  // O^T accumulators [jq][jd]: C col=l15=q, row=quad*4+r = d within jd*16
  f32x4 Oacc[2][4] = {};
  float m_run[2] = {-__builtin_inff(), -__builtin_inff()};
  float l_run[2] = {0.f, 0.f};

  // prefetch tile 0
  ushort8v kpre[2], vpre[2];
  #pragma unroll
  for (int r = 0; r < 2; ++r) {
    int i = tid + 256 * r;
    kpre[r] = *(const ushort8v*)(Kb + (size_t)(i >> 3) * 64 + (i & 7) * 8);
    vpre[r] = *(const ushort8v*)(Vb + (size_t)(i >> 3) * T + (i & 7) * 8);
  }

  // ---- loop 1: kt in [0, qtA] — both jq active (dual MFMA per frag read) ----
  for (int kt = 0; kt <= qtA; ++kt) {
    __syncthreads();
    #pragma unroll
    for (int r = 0; r < 2; ++r) {
      int i = tid + 256 * r;
      *(ushort8v*)&Ks[(i >> 3) * 72 + (i & 7) * 8] = kpre[r];
      *(ushort8v*)&Vs[(i >> 3) * 72 + (i & 7) * 8] = vpre[r];
    }
    __syncthreads();
    {  // prefetch kt+1 (always exists: kt+1 <= qtA+1 <= qtB)
      #pragma unroll
      for (int r = 0; r < 2; ++r) {
        int i = tid + 256 * r;
        kpre[r] = *(const ushort8v*)(Kb + (size_t)((kt + 1) * 64 + (i >> 3)) * 64 + (i & 7) * 8);
        vpre[r] = *(const ushort8v*)(Vb + (size_t)(i >> 3) * T + (kt + 1) * 64 + (i & 7) * 8);
      }
    }

    f32x4 S[4][2] = {};
    #pragma unroll
    for (int s = 0; s < 2; ++s)
      #pragma unroll
      for (int mi = 0; mi < 4; ++mi) {
        short8 kf = *(const short8*)&Ks[(mi * 16 + l15) * 72 + quad * 8 + 32 * s];
        #pragma unroll
        for (int jq = 0; jq < 2; ++jq)
          S[mi][jq] = __builtin_amdgcn_mfma_f32_16x16x32_bf16(kf, qf[jq][s], S[mi][jq], 0, 0, 0);
      }

    if (kt == qtA) {  // diagonal of light tile: mask jq0 (jq1 rows are all beyond this tile)
      int ql = wave * 16 + l15;
      #pragma unroll
      for (int mi = 0; mi < 4; ++mi) {
        int tokl = mi * 16 + quad * 4;
        #pragma unroll
        for (int r = 0; r < 4; ++r)
          if (tokl + r > ql) S[mi][0][r] = -__builtin_inff();
      }
    }

    float alpha[2];
    #pragma unroll
    for (int jq = 0; jq < 2; ++jq) {
      float vmax = -__builtin_inff();
      #pragma unroll
      for (int mi = 0; mi < 4; ++mi)
        #pragma unroll
        for (int r = 0; r < 4; ++r)
          vmax = fmaxf(vmax, S[mi][jq][r]);
      vmax = fmaxf(vmax, __shfl_xor(vmax, 16));
      vmax = fmaxf(vmax, __shfl_xor(vmax, 32));
      float mnew = fmaxf(m_run[jq], vmax);
      alpha[jq] = __expf(m_run[jq] - mnew);
      m_run[jq] = mnew;
      float rs = 0.f;
      #pragma unroll
      for (int mi = 0; mi < 4; ++mi) {
        float p0 = __expf(S[mi][jq][0] - mnew);
        float p1 = __expf(S[mi][jq][1] - mnew);
        float p2 = __expf(S[mi][jq][2] - mnew);
        float p3 = __expf(S[mi][jq][3] - mnew);
        rs += (p0 + p1) + (p2 + p3);
        uint2 pk;
        pk.x = pk_bf16(p0, p1);
        pk.y = pk_bf16(p2, p3);
        *(uint2*)&Ps[wave][(jq * 16 + l15) * 72 + mi * 16 + quad * 4] = pk;
      }
      rs += __shfl_xor(rs, 16);
      rs += __shfl_xor(rs, 32);
      l_run[jq] = l_run[jq] * alpha[jq] + rs;
    }

    #pragma unroll
    for (int jq = 0; jq < 2; ++jq)
      #pragma unroll
      for (int jd = 0; jd < 4; ++jd)
        #pragma unroll
        for (int r = 0; r < 4; ++r)
          Oacc[jq][jd][r] *= alpha[jq];

    #pragma unroll
    for (int s = 0; s < 2; ++s) {
      short8 vfr[4];
      #pragma unroll
      for (int jd = 0; jd < 4; ++jd)
        vfr[jd] = *(const short8*)&Vs[(jd * 16 + l15) * 72 + s * 32 + quad * 8];
      #pragma unroll
      for (int jq = 0; jq < 2; ++jq) {
        short8 pf = *(const short8*)&Ps[wave][(jq * 16 + l15) * 72 + s * 32 + quad * 8];
        #pragma unroll
        for (int jd = 0; jd < 4; ++jd)
          Oacc[jq][jd] = __builtin_amdgcn_mfma_f32_16x16x32_bf16(vfr[jd], pf, Oacc[jq][jd], 0, 0, 0);
      }
    }
  }

  // ---- loop 2: kt in (qtA, qtB] — heavy tile only ----
  for (int kt = qtA + 1; kt <= qtB; ++kt) {
    __syncthreads();
    #pragma unroll
    for (int r = 0; r < 2; ++r) {
      int i = tid + 256 * r;
      *(ushort8v*)&Ks[(i >> 3) * 72 + (i & 7) * 8] = kpre[r];
      *(ushort8v*)&Vs[(i >> 3) * 72 + (i & 7) * 8] = vpre[r];
    }
    __syncthreads();
    if (kt < qtB) {
      #pragma unroll
      for (int r = 0; r < 2; ++r) {
        int i = tid + 256 * r;
        kpre[r] = *(const ushort8v*)(Kb + (size_t)((kt + 1) * 64 + (i >> 3)) * 64 + (i & 7) * 8);
        vpre[r] = *(const ushort8v*)(Vb + (size_t)(i >> 3) * T + (kt + 1) * 64 + (i & 7) * 8);
      }
    }

    f32x4 S[4] = {};
    #pragma unroll
    for (int s = 0; s < 2; ++s)
      #pragma unroll
      for (int mi = 0; mi < 4; ++mi) {
        short8 kf = *(const short8*)&Ks[(mi * 16 + l15) * 72 + quad * 8 + 32 * s];
        S[mi] = __builtin_amdgcn_mfma_f32_16x16x32_bf16(kf, qf[1][s], S[mi], 0, 0, 0);
      }

    if (kt == qtB) {  // diagonal of heavy tile
      int ql = wave * 16 + l15;
      #pragma unroll
      for (int mi = 0; mi < 4; ++mi) {
        int tokl = mi * 16 + quad * 4;
        #pragma unroll
        for (int r = 0; r < 4; ++r)
          if (tokl + r > ql) S[mi][r] = -__builtin_inff();
      }
    }

    float vmax = -__builtin_inff();
    #pragma unroll
    for (int mi = 0; mi < 4; ++mi)
      #pragma unroll
      for (int r = 0; r < 4; ++r)
        vmax = fmaxf(vmax, S[mi][r]);
    vmax = fmaxf(vmax, __shfl_xor(vmax, 16));
    vmax = fmaxf(vmax, __shfl_xor(vmax, 32));
    float mnew = fmaxf(m_run[1], vmax);
    float alpha = __expf(m_run[1] - mnew);
    m_run[1] = mnew;
    float rs = 0.f;
    #pragma unroll
    for (int mi = 0; mi < 4; ++mi) {
      float p0 = __expf(S[mi][0] - mnew);
      float p1 = __expf(S[mi][1] - mnew);
      float p2 = __expf(S[mi][2] - mnew);
      float p3 = __expf(S[mi][3] - mnew);
      rs += (p0 + p1) + (p2 + p3);
      uint2 pk;
      pk.x = pk_bf16(p0, p1);
      pk.y = pk_bf16(p2, p3);
      *(uint2*)&Ps[wave][(16 + l15) * 72 + mi * 16 + quad * 4] = pk;
    }
    rs += __shfl_xor(rs, 16);
    rs += __shfl_xor(rs, 32);
    l_run[1] = l_run[1] * alpha + rs;

    #pragma unroll
    for (int jd = 0; jd < 4; ++jd)
      #pragma unroll
      for (int r = 0; r < 4; ++r)
        Oacc[1][jd][r] *= alpha;

    #pragma unroll
    for (int s = 0; s < 2; ++s) {
      short8 pf = *(const short8*)&Ps[wave][(16 + l15) * 72 + s * 32 + quad * 8];
      #pragma unroll
      for (int jd = 0; jd < 4; ++jd) {
        short8 vfr = *(const short8*)&Vs[(jd * 16 + l15) * 72 + s * 32 + quad * 8];
        Oacc[1][jd] = __builtin_amdgcn_mfma_f32_16x16x32_bf16(vfr, pf, Oacc[1][jd], 0, 0, 0);
      }
    }
  }

  // finalize both tiles: O^T/l per-lane; Y write b64 per jd
  #pragma unroll
  for (int jq = 0; jq < 2; ++jq) {
    float linv = 1.f / l_run[jq];
    int q = qw[jq] + l15;
    size_t row = (size_t)(b * 2048 + q) * 1024 + h * 64 + quad * 4;
    #pragma unroll
    for (int jd = 0; jd < 4; ++jd) {
      uint2 pk;
      pk.x = pk_bf16(Oacc[jq][jd][0] * linv, Oacc[jq][jd][1] * linv);
      pk.y = pk_bf16(Oacc[jq][jd][2] * linv, Oacc[jq][jd][3] * linv);
      *(uint2*)(Yg + row + jd * 16) = pk;
    }
  }
}

// ---------------- out projection: split-K atomics onto bias-seeded out ----------------

__global__ __launch_bounds__(256) void oproj(
    const unsigned short* __restrict__ Y, const unsigned short* __restrict__ Wot,
    float* __restrict__ out) {
  __shared__ __align__(16) unsigned short As[64 * 32];
  __shared__ __align__(16) unsigned short Bs[64 * 32];
  int m0 = blockIdx.x * 64;
  int kbase = blockIdx.y * 256;  // 4-way split-K
  int tid = threadIdx.x, lane = tid & 63, wave = tid >> 6;
  int l15 = lane & 15, quad = lane >> 4;
  f32x4 acc[4] = {};
  for (int k0 = kbase; k0 < kbase + 256; k0 += 32) {
    __syncthreads();
    {
      int row = tid >> 2, c8 = (tid & 3) * 8;
      gload_lds16(Y + (size_t)(m0 + row) * 1024 + k0 + c8, &As[tid * 8]);
      gload_lds16(Wot + (size_t)row * 1024 + k0 + c8, &Bs[tid * 8]);
    }
    __syncthreads();
    short8 af = *(const short8*)&As[(wave * 16 + l15) * 32 + quad * 8];
    #pragma unroll
    for (int j = 0; j < 4; ++j) {
      short8 bf = *(const short8*)&Bs[(j * 16 + l15) * 32 + quad * 8];
      acc[j] = __builtin_amdgcn_mfma_f32_16x16x32_bf16(af, bf, acc[j], 0, 0, 0);
    }
  }
  #pragma unroll
  for (int j = 0; j < 4; ++j) {
    int n = j * 16 + l15;
    #pragma unroll
    for (int r = 0; r < 4; ++r) {
      int m = m0 + wave * 16 + quad * 4 + r;
      atomicAdd(&out[(size_t)m * 64 + n], acc[j][r]);
    }
  }
}

// ---------------- launcher (4 kernels total) ----------------

extern "C" void kernel_launch(void* const* d_in, const int* in_sizes, int n_in,
                              void* d_out, int out_size, void* d_ws, size_t ws_size,
                              hipStream_t stream) {
  const float* x  = (const float*)d_in[0];
  const float* Wq = (const float*)d_in[1];
  const float* Wk = (const float*)d_in[2];
  const float* Wv = (const float*)d_in[3];
  const float* Wo = (const float*)d_in[4];
  const float* bo = (const float*)d_in[5];
  float* out = (float*)d_out;
  char* ws = (char*)d_ws;

  unsigned short* xb  = (unsigned short*)(ws);                       // 8 MB  [4096][1024]
  unsigned short* wqt = (unsigned short*)(ws + (8ull << 20));        // 2 MB  Wq^T
  unsigned short* wkt = (unsigned short*)(ws + (10ull << 20));       // 2 MB
  unsigned short* wvt = (unsigned short*)(ws + (12ull << 20));       // 2 MB
  unsigned short* wot = (unsigned short*)(ws + (14ull << 20));       // 128 KB Wo^T
  unsigned short* q   = (unsigned short*)(ws + (15ull << 20));       // 8 MB  [b][h][t][d]
  unsigned short* k   = (unsigned short*)(ws + (23ull << 20));       // 8 MB  [b][h][t][d]
  unsigned short* vt  = (unsigned short*)(ws + (31ull << 20));       // 8 MB  [b][h][d][t]
  unsigned short* y   = (unsigned short*)(ws + (39ull << 20));       // 8 MB  [4096][1024]

  prep<<<7488, 256, 0, stream>>>(x, Wq, Wk, Wv, Wo, bo, xb, wqt, wkt, wvt, wot, out);
  qkv_gemm<<<dim3(32, 8, 3), 256, 0, stream>>>(xb, wqt, wkt, wvt, q, k, vt);
  attn10<<<dim3(32, 16), 256, 0, stream>>>(q, k, vt, y);
  oproj<<<dim3(64, 4), 256, 0, stream>>>(y, wot, out);
}